// Round 7
// baseline (367.759 us; speedup 1.0000x reference)
//
#include <hip/hip_runtime.h>

#define N_NODESC 20000
#define N_EDGESC 1280000
#define NB 256          // csr-build blocks
#define EPB 5000        // edges per build block

typedef short bf16x8 __attribute__((ext_vector_type(8)));
typedef float f32x4 __attribute__((ext_vector_type(4)));

// ---- workspace layout (bytes, 16B-aligned) ----
constexpr size_t OFF_DEG      = 0;          // int[20000]
constexpr size_t OFF_ROWSTART = 81920;      // int[20001]
constexpr size_t OFF_INVDEG   = 163840;     // float[20000]
constexpr size_t OFF_ACCUM    = 245760;     // float[4]
constexpr size_t OFF_DONE     = 245776;     // int[4]
constexpr size_t OFF_BSUM     = 245792;     // int[128]
constexpr size_t OFF_BOFF     = 246304;     // int[128]
constexpr size_t OFF_S1       = 246816;     // float[20000]
constexpr size_t OFF_T1      = 326816;      // float[20000]
constexpr size_t OFF_HIST     = 406816;     // ushort[256][20000] = 10.24 MB
constexpr size_t OFF_CSR      = 10646816;   // ushort[1280000] (+128B overread pad)
constexpr size_t OFF_XB       = 13206944;   // bf16[20000][256] row-major = 10.24 MB
constexpr size_t OFF_MEANB    = 23446944;   // bf16[20000][256]
constexpr size_t OFF_W1LB     = 33686944;   // bf16[256][256]
constexpr size_t OFF_W1RB     = 33818016;   // bf16[256][256] (end ~33.9 MB)

static __device__ __forceinline__ unsigned f2bf(float f) {
    unsigned u = __float_as_uint(f);
    return ((u + 0x7fffu + ((u >> 16) & 1u)) >> 16) & 0xffffu;  // RTNE
}
static __device__ __forceinline__ float bflo(unsigned w) {
    return __uint_as_float(w << 16);
}
static __device__ __forceinline__ float bfhi(unsigned w) {
    return __uint_as_float(w & 0xffff0000u);
}

// cast x, W1_l, W1_r to bf16 (8 floats / thread); fused zero of s1/t1/accum/done/bsum
__global__ void __launch_bounds__(256) k_cast(
        const float4* __restrict__ x, const float4* __restrict__ w1l,
        const float4* __restrict__ w1r, uint4* __restrict__ xb,
        uint4* __restrict__ w1lb, uint4* __restrict__ w1rb,
        float* __restrict__ s1, float* __restrict__ t1,
        float* __restrict__ accum, int* __restrict__ done,
        int* __restrict__ bsum) {
    int g = blockIdx.x * 256 + threadIdx.x;   // 8-float group id
    if (g < N_NODESC) { s1[g] = 0.0f; t1[g] = 0.0f; }
    if (g < 128) bsum[g] = 0;
    if (g == 0) { accum[0] = 0.0f; done[0] = 0; }
    const float4* src; uint4* dst; int off;
    if (g < 640000)      { src = x;   dst = xb;   off = g; }
    else if (g < 648192) { src = w1l; dst = w1lb; off = g - 640000; }
    else                 { src = w1r; dst = w1rb; off = g - 648192; }
    float4 a = src[off * 2], b = src[off * 2 + 1];
    uint4 o;
    o.x = f2bf(a.x) | (f2bf(a.y) << 16);
    o.y = f2bf(a.z) | (f2bf(a.w) << 16);
    o.z = f2bf(b.x) | (f2bf(b.y) << 16);
    o.w = f2bf(b.z) | (f2bf(b.w) << 16);
    dst[off] = o;
}

// per-block LDS histogram of dst (two 16-bit counters packed per word)
__global__ void __launch_bounds__(256) k_hist(const int* __restrict__ ei,
                                              unsigned short* __restrict__ hist) {
    __shared__ unsigned int lh[10000];
    int b = blockIdx.x, t = threadIdx.x;
    for (int w = t; w < 10000; w += 256) lh[w] = 0;
    __syncthreads();
    int base = b * EPB;
    for (int i = t; i < EPB; i += 256) {
        int d = ei[N_EDGESC + base + i];
        atomicAdd(&lh[d >> 1], (d & 1) ? 0x10000u : 1u);
    }
    __syncthreads();
    unsigned int* gh = (unsigned int*)(hist + (size_t)b * N_NODESC);
    for (int w = t; w < 10000; w += 256) gh[w] = lh[w];
}

// per bin: exclusive prefix across 256 build blocks (values cached in VGPRs);
// deg[bin] total; fused block-sum into bsum via atomics
__global__ void __launch_bounds__(256) k_prefix(unsigned short* __restrict__ hist,
                                                int* __restrict__ deg,
                                                int* __restrict__ bsum) {
    __shared__ int wtot[4][64];
    int t = threadIdx.x;
    int lb = t & 63, sub = t >> 6;
    int bin = blockIdx.x * 64 + lb;
    bool ok = bin < N_NODESC;
    int vals[64];
    int run = 0;
    if (ok) {
        #pragma unroll
        for (int i = 0; i < 64; i++) {
            vals[i] = hist[(size_t)(sub * 64 + i) * N_NODESC + bin];
            run += vals[i];
        }
    }
    wtot[sub][lb] = run;
    __syncthreads();
    int off = 0, total = 0;
    for (int w = 0; w < 4; w++) {
        int v = wtot[w][lb];
        if (w < sub) off += v;
        total += v;
    }
    if (sub == 0) {
        int tv = ok ? total : 0;
        if (ok) deg[bin] = total;
        #pragma unroll
        for (int o2 = 32; o2 > 0; o2 >>= 1) tv += __shfl_down(tv, o2);
        if (lb == 0) atomicAdd(&bsum[(blockIdx.x * 64) >> 8], tv);
    }
    if (ok) {
        int run2 = off;
        #pragma unroll
        for (int i = 0; i < 64; i++) {
            hist[(size_t)(sub * 64 + i) * N_NODESC + bin] = (unsigned short)run2;
            run2 += vals[i];
        }
    }
}

__global__ void k_scan2(const int* __restrict__ bsum, int* __restrict__ boff,
                        int* __restrict__ row_start) {
    __shared__ int sm[128];
    int t = threadIdx.x;
    int v = (t < 79) ? bsum[t] : 0;
    sm[t] = v;
    __syncthreads();
    for (int off = 1; off < 128; off <<= 1) {
        int add = (t >= off) ? sm[t - off] : 0;
        __syncthreads();
        sm[t] += add;
        __syncthreads();
    }
    if (t < 79) boff[t] = sm[t] - v;
    if (t == 0) row_start[N_NODESC] = sm[127];
}

__global__ void __launch_bounds__(256) k_scan3(
        const int* __restrict__ deg, const int* __restrict__ boff,
        int* __restrict__ row_start, float* __restrict__ inv_deg) {
    __shared__ int wsum[4];
    int i = blockIdx.x * 256 + threadIdx.x;
    int lane = threadIdx.x & 63, wid = threadIdx.x >> 6;
    int v = (i < N_NODESC) ? deg[i] : 0;
    int incl = v;
    #pragma unroll
    for (int off = 1; off < 64; off <<= 1) {
        int n = __shfl_up(incl, off);
        if (lane >= off) incl += n;
    }
    if (lane == 63) wsum[wid] = incl;
    __syncthreads();
    int wpre = 0;
    #pragma unroll
    for (int w = 0; w < 4; w++) wpre += (w < wid) ? wsum[w] : 0;
    if (i < N_NODESC) {
        row_start[i] = boff[blockIdx.x] + wpre + incl - v;
        inv_deg[i]   = 1.0f / (float)max(v, 1);
    }
}

// scatter edges into CSR (ushort src ids): rank via LDS atomics + hist prefix
__global__ void __launch_bounds__(256) k_fill2(const int* __restrict__ ei,
        const int* __restrict__ row_start, const unsigned short* __restrict__ hist,
        unsigned short* __restrict__ csr) {
    __shared__ unsigned int lh[10000];
    int b = blockIdx.x, t = threadIdx.x;
    for (int w = t; w < 10000; w += 256) lh[w] = 0;
    __syncthreads();
    int base = b * EPB;
    const unsigned short* hb = hist + (size_t)b * N_NODESC;
    for (int i = t; i < EPB; i += 256) {
        int e = base + i;
        int d = ei[N_EDGESC + e];
        int s = ei[e];
        unsigned int old = atomicAdd(&lh[d >> 1], (d & 1) ? 0x10000u : 1u);
        int rank = (d & 1) ? (int)(old >> 16) : (int)(old & 0xffffu);
        int pos = row_start[d] + (int)hb[d] + rank;
        csr[pos] = (unsigned short)s;
    }
}

// one wave per node, lane owns 4 bf16 channels (8B). Edge index wave-uniform
// via readlane (SGPR base + invariant lane offset). 16-deep load unroll,
// 2 accumulator chains, csr block prefetched one iteration ahead.
__global__ void __launch_bounds__(256) k_agg(const uint2* __restrict__ xb2,
        const int* __restrict__ row_start, const unsigned short* __restrict__ csr,
        const float* __restrict__ inv_deg, uint2* __restrict__ meanb2) {
    int wid = threadIdx.x >> 6, lane = threadIdx.x & 63;
    int node = blockIdx.x * 4 + wid;
    int start = row_start[node], end = row_start[node + 1];
    float a0 = 0.f, a1 = 0.f, a2 = 0.f, a3 = 0.f;
    float c0 = 0.f, c1 = 0.f, c2 = 0.f, c3 = 0.f;
    int idx = (start < end) ? (int)csr[start + lane] : 0;  // <=126B overread ok
    for (int j = start; j < end; j += 64) {
        int cnt = min(64, end - j);
        int idxn = (j + 64 < end) ? (int)csr[j + 64 + lane] : 0;
        int k = 0;
        for (; k + 16 <= cnt; k += 16) {
            #pragma unroll
            for (int u = 0; u < 16; u += 2) {
                int s0 = __builtin_amdgcn_readlane(idx, k + u);
                int s1 = __builtin_amdgcn_readlane(idx, k + u + 1);
                uint2 v0 = xb2[(size_t)s0 * 64 + lane];
                uint2 v1 = xb2[(size_t)s1 * 64 + lane];
                a0 += bflo(v0.x); a1 += bfhi(v0.x);
                a2 += bflo(v0.y); a3 += bfhi(v0.y);
                c0 += bflo(v1.x); c1 += bfhi(v1.x);
                c2 += bflo(v1.y); c3 += bfhi(v1.y);
            }
        }
        for (; k < cnt; k++) {
            int s0 = __builtin_amdgcn_readlane(idx, k);
            uint2 v = xb2[(size_t)s0 * 64 + lane];
            a0 += bflo(v.x); a1 += bfhi(v.x);
            a2 += bflo(v.y); a3 += bfhi(v.y);
        }
        idx = idxn;
    }
    float inv = inv_deg[node];
    uint2 o;
    o.x = f2bf((a0 + c0) * inv) | (f2bf((a1 + c1) * inv) << 16);
    o.y = f2bf((a2 + c2) * inv) | (f2bf((a3 + c3) * inv) << 16);
    meanb2[(size_t)node * 64 + lane] = o;
}

// h1 = relu([mean|x] @ [W1l|W1r]^T + b1) via bf16 MFMA (fp32 accum), fused
// epilogue s1 += h1.w2l, t1 += h1.w2r. 64x64 tile, BK=64, 4 waves.
__global__ void __launch_bounds__(256) k_gemm(const uint4* __restrict__ meanb4,
        const uint4* __restrict__ xb4, const uint4* __restrict__ w1lb4,
        const uint4* __restrict__ w1rb4, const float* __restrict__ b1,
        const float* __restrict__ w2l, const float* __restrict__ w2r,
        float* __restrict__ s1, float* __restrict__ t1) {
    __shared__ __align__(16) unsigned short As[64][72];
    __shared__ __align__(16) unsigned short Bs[64][72];
    int t = threadIdx.x;
    int m0 = blockIdx.x * 64, n0 = blockIdx.y * 64;
    int wv = t >> 6, l = t & 63, lr = l & 15, quad = l >> 4;
    f32x4 acc[4] = {{0,0,0,0},{0,0,0,0},{0,0,0,0},{0,0,0,0}};
    for (int kt = 0; kt < 8; kt++) {
        const uint4* Asrc = (kt < 4) ? meanb4 : xb4;
        const uint4* Bsrc = (kt < 4) ? w1lb4 : w1rb4;
        int k0q = (kt & 3) * 8;
        #pragma unroll
        for (int p = 0; p < 2; p++) {
            int f = t + p * 256;
            int row = f >> 3, cc = f & 7;
            int m = m0 + row;
            uint4 va = (m < N_NODESC) ? Asrc[(size_t)m * 32 + k0q + cc]
                                      : make_uint4(0, 0, 0, 0);
            uint4 vb = Bsrc[(size_t)(n0 + row) * 32 + k0q + cc];
            *(uint4*)&As[row][cc * 8] = va;
            *(uint4*)&Bs[row][cc * 8] = vb;
        }
        __syncthreads();
        #pragma unroll
        for (int ks = 0; ks < 64; ks += 32) {
            bf16x8 af = *(const bf16x8*)&As[wv * 16 + lr][ks + quad * 8];
            #pragma unroll
            for (int jj = 0; jj < 4; jj++) {
                bf16x8 bf = *(const bf16x8*)&Bs[jj * 16 + lr][ks + quad * 8];
                acc[jj] = __builtin_amdgcn_mfma_f32_16x16x32_bf16(
                              af, bf, acc[jj], 0, 0, 0);
            }
        }
        __syncthreads();
    }
    float ps[4] = {0, 0, 0, 0}, pt[4] = {0, 0, 0, 0};
    #pragma unroll
    for (int jj = 0; jj < 4; jj++) {
        int col = n0 + jj * 16 + lr;
        float bb = b1[col], wl = w2l[col], wr = w2r[col];
        #pragma unroll
        for (int r = 0; r < 4; r++) {
            float h = fmaxf(acc[jj][r] + bb, 0.0f);
            ps[r] += h * wl; pt[r] += h * wr;
        }
    }
    #pragma unroll
    for (int r = 0; r < 4; r++) {
        #pragma unroll
        for (int off = 8; off > 0; off >>= 1) {
            ps[r] += __shfl_down(ps[r], off, 16);
            pt[r] += __shfl_down(pt[r], off, 16);
        }
    }
    if (lr == 0) {
        int mb = m0 + wv * 16 + quad * 4;
        #pragma unroll
        for (int r = 0; r < 4; r++) {
            int m = mb + r;
            if (m < N_NODESC) {
                atomicAdd(&s1[m], ps[r]);
                atomicAdd(&t1[m], pt[r]);
            }
        }
    }
}

// layer-2 scalar aggregation + epilogue + fc dot; last block writes out
__global__ void __launch_bounds__(256) k_layer2(
        const int* __restrict__ row_start, const unsigned short* __restrict__ csr,
        const float* __restrict__ inv_deg, const float* __restrict__ s1,
        const float* __restrict__ t1, const float* __restrict__ b2,
        const float* __restrict__ fc_w, float* __restrict__ accum,
        int* __restrict__ done, const float* __restrict__ fc_b,
        float* __restrict__ out) {
    __shared__ float part[4];
    int wid = threadIdx.x >> 6, lane = threadIdx.x & 63;
    int node = blockIdx.x * 4 + wid;
    float contrib = 0.0f;
    if (node < N_NODESC) {
        int start = row_start[node], end = row_start[node + 1];
        float s = 0.0f;
        for (int j = start + lane; j < end; j += 64) s += s1[csr[j]];
        #pragma unroll
        for (int off = 32; off > 0; off >>= 1) s += __shfl_down(s, off);
        if (lane == 0) {
            float h2 = fmaxf(s * inv_deg[node] + b2[0] + t1[node], 0.0f);
            contrib = h2 * fc_w[node];
        }
    }
    if (lane == 0) part[wid] = contrib;
    __syncthreads();
    if (threadIdx.x == 0) {
        atomicAdd(accum, part[0] + part[1] + part[2] + part[3]);
        __threadfence();
        int old = atomicAdd(done, 1);
        if (old == 4999) {
            float v = atomicAdd(accum, 0.0f);   // coherent read of final sum
            out[0] = v + fc_b[0];
        }
    }
}

extern "C" void kernel_launch(void* const* d_in, const int* in_sizes, int n_in,
                              void* d_out, int out_size, void* d_ws, size_t ws_size,
                              hipStream_t stream) {
    const float* x    = (const float*)d_in[0];
    const int*   ei   = (const int*)d_in[1];
    const float* w1l  = (const float*)d_in[2];
    const float* b1   = (const float*)d_in[3];
    const float* w1r  = (const float*)d_in[4];
    const float* w2l  = (const float*)d_in[5];
    const float* b2   = (const float*)d_in[6];
    const float* w2r  = (const float*)d_in[7];
    const float* fcw  = (const float*)d_in[8];
    const float* fcb  = (const float*)d_in[9];
    float* out = (float*)d_out;

    char* ws = (char*)d_ws;
    int*    deg       = (int*)(ws + OFF_DEG);
    int*    row_start = (int*)(ws + OFF_ROWSTART);
    float*  inv_deg   = (float*)(ws + OFF_INVDEG);
    float*  accum     = (float*)(ws + OFF_ACCUM);
    int*    done      = (int*)(ws + OFF_DONE);
    int*    bsum      = (int*)(ws + OFF_BSUM);
    int*    boff      = (int*)(ws + OFF_BOFF);
    float*  s1        = (float*)(ws + OFF_S1);
    float*  t1        = (float*)(ws + OFF_T1);
    unsigned short* hist = (unsigned short*)(ws + OFF_HIST);
    unsigned short* csr  = (unsigned short*)(ws + OFF_CSR);
    uint2*  xb2       = (uint2*)(ws + OFF_XB);
    uint2*  meanb2    = (uint2*)(ws + OFF_MEANB);
    uint4*  w1lb4     = (uint4*)(ws + OFF_W1LB);
    uint4*  w1rb4     = (uint4*)(ws + OFF_W1RB);

    k_cast<<<2564, 256, 0, stream>>>((const float4*)x, (const float4*)w1l,
                                     (const float4*)w1r, (uint4*)xb2,
                                     w1lb4, w1rb4, s1, t1, accum, done, bsum);
    k_hist<<<NB, 256, 0, stream>>>(ei, hist);
    k_prefix<<<313, 256, 0, stream>>>(hist, deg, bsum);
    k_scan2<<<1, 128, 0, stream>>>(bsum, boff, row_start);
    k_scan3<<<79, 256, 0, stream>>>(deg, boff, row_start, inv_deg);
    k_fill2<<<NB, 256, 0, stream>>>(ei, row_start, hist, csr);
    k_agg<<<5000, 256, 0, stream>>>((const uint2*)xb2, row_start, csr, inv_deg,
                                    meanb2);
    dim3 ggrid(313, 4);
    k_gemm<<<ggrid, 256, 0, stream>>>((const uint4*)meanb2, (const uint4*)xb2,
                                      (const uint4*)w1lb4, (const uint4*)w1rb4,
                                      b1, w2l, w2r, s1, t1);
    k_layer2<<<5000, 256, 0, stream>>>(row_start, csr, inv_deg, s1, t1, b2,
                                       fcw, accum, done, fcb, out);
}

// Round 8
// 231.042 us; speedup vs baseline: 1.5917x; 1.5917x over previous
//
#include <hip/hip_runtime.h>

#define N_NODESC 20000
#define N_EDGESC 1280000
#define NB 256          // csr-build blocks
#define EPB 5000        // edges per build block

typedef short bf16x8 __attribute__((ext_vector_type(8)));
typedef float f32x4 __attribute__((ext_vector_type(4)));

// ---- workspace layout (bytes, 16B-aligned) ----
constexpr size_t OFF_DEG      = 0;          // int[20000]
constexpr size_t OFF_ROWSTART = 81920;      // int[20001]
constexpr size_t OFF_INVDEG   = 163840;     // float[20000]
constexpr size_t OFF_BSUM     = 245760;     // int[128]
constexpr size_t OFF_BOFF     = 246272;     // int[128]
constexpr size_t OFF_S1       = 246784;     // float[20000]
constexpr size_t OFF_T1       = 326784;     // float[20000]
constexpr size_t OFF_PART     = 406784;     // float[5120] block partials
constexpr size_t OFF_HIST     = 427264;     // ushort[256][20000] = 10.24 MB
constexpr size_t OFF_CSR      = 10667264;   // ushort[1280000] (+128B overread pad)
constexpr size_t OFF_XB       = 13227392;   // bf16[20000][256] row-major = 10.24 MB
constexpr size_t OFF_MEANB    = 23467392;   // bf16[20000][256]
constexpr size_t OFF_W1LB     = 33707392;   // bf16[256][256]
constexpr size_t OFF_W1RB     = 33838464;   // bf16[256][256] (end ~34 MB)

static __device__ __forceinline__ unsigned f2bf(float f) {
    unsigned u = __float_as_uint(f);
    return ((u + 0x7fffu + ((u >> 16) & 1u)) >> 16) & 0xffffu;  // RTNE
}
static __device__ __forceinline__ float bflo(unsigned w) {
    return __uint_as_float(w << 16);
}
static __device__ __forceinline__ float bfhi(unsigned w) {
    return __uint_as_float(w & 0xffff0000u);
}

// cast x, W1_l, W1_r to bf16 (8 floats / thread); fused zero of s1/t1/bsum
__global__ void __launch_bounds__(256) k_cast(
        const float4* __restrict__ x, const float4* __restrict__ w1l,
        const float4* __restrict__ w1r, uint4* __restrict__ xb,
        uint4* __restrict__ w1lb, uint4* __restrict__ w1rb,
        float* __restrict__ s1, float* __restrict__ t1,
        int* __restrict__ bsum) {
    int g = blockIdx.x * 256 + threadIdx.x;   // 8-float group id
    if (g < N_NODESC) { s1[g] = 0.0f; t1[g] = 0.0f; }
    if (g < 128) bsum[g] = 0;
    const float4* src; uint4* dst; int off;
    if (g < 640000)      { src = x;   dst = xb;   off = g; }
    else if (g < 648192) { src = w1l; dst = w1lb; off = g - 640000; }
    else                 { src = w1r; dst = w1rb; off = g - 648192; }
    float4 a = src[off * 2], b = src[off * 2 + 1];
    uint4 o;
    o.x = f2bf(a.x) | (f2bf(a.y) << 16);
    o.y = f2bf(a.z) | (f2bf(a.w) << 16);
    o.z = f2bf(b.x) | (f2bf(b.y) << 16);
    o.w = f2bf(b.z) | (f2bf(b.w) << 16);
    dst[off] = o;
}

// per-block LDS histogram of dst (two 16-bit counters packed per word)
__global__ void __launch_bounds__(256) k_hist(const int* __restrict__ ei,
                                              unsigned short* __restrict__ hist) {
    __shared__ unsigned int lh[10000];
    int b = blockIdx.x, t = threadIdx.x;
    for (int w = t; w < 10000; w += 256) lh[w] = 0;
    __syncthreads();
    int base = b * EPB;
    for (int i = t; i < EPB; i += 256) {
        int d = ei[N_EDGESC + base + i];
        atomicAdd(&lh[d >> 1], (d & 1) ? 0x10000u : 1u);
    }
    __syncthreads();
    unsigned int* gh = (unsigned int*)(hist + (size_t)b * N_NODESC);
    for (int w = t; w < 10000; w += 256) gh[w] = lh[w];
}

// per bin: exclusive prefix across 256 build blocks (values cached in VGPRs);
// deg[bin] total; fused block-sum into bsum via atomics
__global__ void __launch_bounds__(256) k_prefix(unsigned short* __restrict__ hist,
                                                int* __restrict__ deg,
                                                int* __restrict__ bsum) {
    __shared__ int wtot[4][64];
    int t = threadIdx.x;
    int lb = t & 63, sub = t >> 6;
    int bin = blockIdx.x * 64 + lb;
    bool ok = bin < N_NODESC;
    int vals[64];
    int run = 0;
    if (ok) {
        #pragma unroll
        for (int i = 0; i < 64; i++) {
            vals[i] = hist[(size_t)(sub * 64 + i) * N_NODESC + bin];
            run += vals[i];
        }
    }
    wtot[sub][lb] = run;
    __syncthreads();
    int off = 0, total = 0;
    for (int w = 0; w < 4; w++) {
        int v = wtot[w][lb];
        if (w < sub) off += v;
        total += v;
    }
    if (sub == 0) {
        int tv = ok ? total : 0;
        if (ok) deg[bin] = total;
        #pragma unroll
        for (int o2 = 32; o2 > 0; o2 >>= 1) tv += __shfl_down(tv, o2);
        if (lb == 0) atomicAdd(&bsum[(blockIdx.x * 64) >> 8], tv);
    }
    if (ok) {
        int run2 = off;
        #pragma unroll
        for (int i = 0; i < 64; i++) {
            hist[(size_t)(sub * 64 + i) * N_NODESC + bin] = (unsigned short)run2;
            run2 += vals[i];
        }
    }
}

__global__ void k_scan2(const int* __restrict__ bsum, int* __restrict__ boff,
                        int* __restrict__ row_start) {
    __shared__ int sm[128];
    int t = threadIdx.x;
    int v = (t < 79) ? bsum[t] : 0;
    sm[t] = v;
    __syncthreads();
    for (int off = 1; off < 128; off <<= 1) {
        int add = (t >= off) ? sm[t - off] : 0;
        __syncthreads();
        sm[t] += add;
        __syncthreads();
    }
    if (t < 79) boff[t] = sm[t] - v;
    if (t == 0) row_start[N_NODESC] = sm[127];
}

__global__ void __launch_bounds__(256) k_scan3(
        const int* __restrict__ deg, const int* __restrict__ boff,
        int* __restrict__ row_start, float* __restrict__ inv_deg) {
    __shared__ int wsum[4];
    int i = blockIdx.x * 256 + threadIdx.x;
    int lane = threadIdx.x & 63, wid = threadIdx.x >> 6;
    int v = (i < N_NODESC) ? deg[i] : 0;
    int incl = v;
    #pragma unroll
    for (int off = 1; off < 64; off <<= 1) {
        int n = __shfl_up(incl, off);
        if (lane >= off) incl += n;
    }
    if (lane == 63) wsum[wid] = incl;
    __syncthreads();
    int wpre = 0;
    #pragma unroll
    for (int w = 0; w < 4; w++) wpre += (w < wid) ? wsum[w] : 0;
    if (i < N_NODESC) {
        row_start[i] = boff[blockIdx.x] + wpre + incl - v;
        inv_deg[i]   = 1.0f / (float)max(v, 1);
    }
}

// scatter edges into CSR (ushort src ids): rank via LDS atomics + hist prefix
__global__ void __launch_bounds__(256) k_fill2(const int* __restrict__ ei,
        const int* __restrict__ row_start, const unsigned short* __restrict__ hist,
        unsigned short* __restrict__ csr) {
    __shared__ unsigned int lh[10000];
    int b = blockIdx.x, t = threadIdx.x;
    for (int w = t; w < 10000; w += 256) lh[w] = 0;
    __syncthreads();
    int base = b * EPB;
    const unsigned short* hb = hist + (size_t)b * N_NODESC;
    for (int i = t; i < EPB; i += 256) {
        int e = base + i;
        int d = ei[N_EDGESC + e];
        int s = ei[e];
        unsigned int old = atomicAdd(&lh[d >> 1], (d & 1) ? 0x10000u : 1u);
        int rank = (d & 1) ? (int)(old >> 16) : (int)(old & 0xffffu);
        int pos = row_start[d] + (int)hb[d] + rank;
        csr[pos] = (unsigned short)s;
    }
}

// one wave per node, lane owns 4 bf16 channels (8B). Edge index wave-uniform
// via readlane (SGPR base + invariant lane offset). 16-deep load unroll,
// 2 accumulator chains, csr block prefetched one iteration ahead.
__global__ void __launch_bounds__(256) k_agg(const uint2* __restrict__ xb2,
        const int* __restrict__ row_start, const unsigned short* __restrict__ csr,
        const float* __restrict__ inv_deg, uint2* __restrict__ meanb2) {
    int wid = threadIdx.x >> 6, lane = threadIdx.x & 63;
    int node = blockIdx.x * 4 + wid;
    int start = row_start[node], end = row_start[node + 1];
    float a0 = 0.f, a1 = 0.f, a2 = 0.f, a3 = 0.f;
    float c0 = 0.f, c1 = 0.f, c2 = 0.f, c3 = 0.f;
    int idx = (start < end) ? (int)csr[start + lane] : 0;  // <=126B overread ok
    for (int j = start; j < end; j += 64) {
        int cnt = min(64, end - j);
        int idxn = (j + 64 < end) ? (int)csr[j + 64 + lane] : 0;
        int k = 0;
        for (; k + 16 <= cnt; k += 16) {
            #pragma unroll
            for (int u = 0; u < 16; u += 2) {
                int s0 = __builtin_amdgcn_readlane(idx, k + u);
                int s1 = __builtin_amdgcn_readlane(idx, k + u + 1);
                uint2 v0 = xb2[(size_t)s0 * 64 + lane];
                uint2 v1 = xb2[(size_t)s1 * 64 + lane];
                a0 += bflo(v0.x); a1 += bfhi(v0.x);
                a2 += bflo(v0.y); a3 += bfhi(v0.y);
                c0 += bflo(v1.x); c1 += bfhi(v1.x);
                c2 += bflo(v1.y); c3 += bfhi(v1.y);
            }
        }
        for (; k < cnt; k++) {
            int s0 = __builtin_amdgcn_readlane(idx, k);
            uint2 v = xb2[(size_t)s0 * 64 + lane];
            a0 += bflo(v.x); a1 += bfhi(v.x);
            a2 += bflo(v.y); a3 += bfhi(v.y);
        }
        idx = idxn;
    }
    float inv = inv_deg[node];
    uint2 o;
    o.x = f2bf((a0 + c0) * inv) | (f2bf((a1 + c1) * inv) << 16);
    o.y = f2bf((a2 + c2) * inv) | (f2bf((a3 + c3) * inv) << 16);
    meanb2[(size_t)node * 64 + lane] = o;
}

// h1 = relu([mean|x] @ [W1l|W1r]^T + b1) via bf16 MFMA (fp32 accum), fused
// epilogue s1 += h1.w2l, t1 += h1.w2r. 64x64 tile, BK=64, 4 waves.
__global__ void __launch_bounds__(256) k_gemm(const uint4* __restrict__ meanb4,
        const uint4* __restrict__ xb4, const uint4* __restrict__ w1lb4,
        const uint4* __restrict__ w1rb4, const float* __restrict__ b1,
        const float* __restrict__ w2l, const float* __restrict__ w2r,
        float* __restrict__ s1, float* __restrict__ t1) {
    __shared__ __align__(16) unsigned short As[64][72];
    __shared__ __align__(16) unsigned short Bs[64][72];
    int t = threadIdx.x;
    int m0 = blockIdx.x * 64, n0 = blockIdx.y * 64;
    int wv = t >> 6, l = t & 63, lr = l & 15, quad = l >> 4;
    f32x4 acc[4] = {{0,0,0,0},{0,0,0,0},{0,0,0,0},{0,0,0,0}};
    for (int kt = 0; kt < 8; kt++) {
        const uint4* Asrc = (kt < 4) ? meanb4 : xb4;
        const uint4* Bsrc = (kt < 4) ? w1lb4 : w1rb4;
        int k0q = (kt & 3) * 8;
        #pragma unroll
        for (int p = 0; p < 2; p++) {
            int f = t + p * 256;
            int row = f >> 3, cc = f & 7;
            int m = m0 + row;
            uint4 va = (m < N_NODESC) ? Asrc[(size_t)m * 32 + k0q + cc]
                                      : make_uint4(0, 0, 0, 0);
            uint4 vb = Bsrc[(size_t)(n0 + row) * 32 + k0q + cc];
            *(uint4*)&As[row][cc * 8] = va;
            *(uint4*)&Bs[row][cc * 8] = vb;
        }
        __syncthreads();
        #pragma unroll
        for (int ks = 0; ks < 64; ks += 32) {
            bf16x8 af = *(const bf16x8*)&As[wv * 16 + lr][ks + quad * 8];
            #pragma unroll
            for (int jj = 0; jj < 4; jj++) {
                bf16x8 bf = *(const bf16x8*)&Bs[jj * 16 + lr][ks + quad * 8];
                acc[jj] = __builtin_amdgcn_mfma_f32_16x16x32_bf16(
                              af, bf, acc[jj], 0, 0, 0);
            }
        }
        __syncthreads();
    }
    float ps[4] = {0, 0, 0, 0}, pt[4] = {0, 0, 0, 0};
    #pragma unroll
    for (int jj = 0; jj < 4; jj++) {
        int col = n0 + jj * 16 + lr;
        float bb = b1[col], wl = w2l[col], wr = w2r[col];
        #pragma unroll
        for (int r = 0; r < 4; r++) {
            float h = fmaxf(acc[jj][r] + bb, 0.0f);
            ps[r] += h * wl; pt[r] += h * wr;
        }
    }
    #pragma unroll
    for (int r = 0; r < 4; r++) {
        #pragma unroll
        for (int off = 8; off > 0; off >>= 1) {
            ps[r] += __shfl_down(ps[r], off, 16);
            pt[r] += __shfl_down(pt[r], off, 16);
        }
    }
    if (lr == 0) {
        int mb = m0 + wv * 16 + quad * 4;
        #pragma unroll
        for (int r = 0; r < 4; r++) {
            int m = mb + r;
            if (m < N_NODESC) {
                atomicAdd(&s1[m], ps[r]);
                atomicAdd(&t1[m], pt[r]);
            }
        }
    }
}

// layer-2 scalar aggregation + epilogue + fc dot; plain-store block partials
// (NO device fence / same-address atomics — r7 showed 5000 per-block
// threadfences cost ~100x more than one extra kernel launch)
__global__ void __launch_bounds__(256) k_layer2(
        const int* __restrict__ row_start, const unsigned short* __restrict__ csr,
        const float* __restrict__ inv_deg, const float* __restrict__ s1,
        const float* __restrict__ t1, const float* __restrict__ b2,
        const float* __restrict__ fc_w, float* __restrict__ part) {
    __shared__ float pw[4];
    int wid = threadIdx.x >> 6, lane = threadIdx.x & 63;
    int node = blockIdx.x * 4 + wid;
    float contrib = 0.0f;
    if (node < N_NODESC) {
        int start = row_start[node], end = row_start[node + 1];
        float s = 0.0f;
        for (int j = start + lane; j < end; j += 64) s += s1[csr[j]];
        #pragma unroll
        for (int off = 32; off > 0; off >>= 1) s += __shfl_down(s, off);
        if (lane == 0) {
            float h2 = fmaxf(s * inv_deg[node] + b2[0] + t1[node], 0.0f);
            contrib = h2 * fc_w[node];
        }
    }
    if (lane == 0) pw[wid] = contrib;
    __syncthreads();
    if (threadIdx.x == 0)
        part[blockIdx.x] = pw[0] + pw[1] + pw[2] + pw[3];
}

// single-block reduction of 5000 partials
__global__ void __launch_bounds__(256) k_final(const float* __restrict__ part,
        const float* __restrict__ fc_b, float* __restrict__ out) {
    __shared__ float sm[4];
    int t = threadIdx.x;
    float s = 0.0f;
    for (int i = t; i < 5000; i += 256) s += part[i];
    #pragma unroll
    for (int off = 32; off > 0; off >>= 1) s += __shfl_down(s, off);
    if ((t & 63) == 0) sm[t >> 6] = s;
    __syncthreads();
    if (t == 0) out[0] = sm[0] + sm[1] + sm[2] + sm[3] + fc_b[0];
}

extern "C" void kernel_launch(void* const* d_in, const int* in_sizes, int n_in,
                              void* d_out, int out_size, void* d_ws, size_t ws_size,
                              hipStream_t stream) {
    const float* x    = (const float*)d_in[0];
    const int*   ei   = (const int*)d_in[1];
    const float* w1l  = (const float*)d_in[2];
    const float* b1   = (const float*)d_in[3];
    const float* w1r  = (const float*)d_in[4];
    const float* w2l  = (const float*)d_in[5];
    const float* b2   = (const float*)d_in[6];
    const float* w2r  = (const float*)d_in[7];
    const float* fcw  = (const float*)d_in[8];
    const float* fcb  = (const float*)d_in[9];
    float* out = (float*)d_out;

    char* ws = (char*)d_ws;
    int*    deg       = (int*)(ws + OFF_DEG);
    int*    row_start = (int*)(ws + OFF_ROWSTART);
    float*  inv_deg   = (float*)(ws + OFF_INVDEG);
    int*    bsum      = (int*)(ws + OFF_BSUM);
    int*    boff      = (int*)(ws + OFF_BOFF);
    float*  s1        = (float*)(ws + OFF_S1);
    float*  t1        = (float*)(ws + OFF_T1);
    float*  part      = (float*)(ws + OFF_PART);
    unsigned short* hist = (unsigned short*)(ws + OFF_HIST);
    unsigned short* csr  = (unsigned short*)(ws + OFF_CSR);
    uint2*  xb2       = (uint2*)(ws + OFF_XB);
    uint2*  meanb2    = (uint2*)(ws + OFF_MEANB);
    uint4*  w1lb4     = (uint4*)(ws + OFF_W1LB);
    uint4*  w1rb4     = (uint4*)(ws + OFF_W1RB);

    k_cast<<<2564, 256, 0, stream>>>((const float4*)x, (const float4*)w1l,
                                     (const float4*)w1r, (uint4*)xb2,
                                     w1lb4, w1rb4, s1, t1, bsum);
    k_hist<<<NB, 256, 0, stream>>>(ei, hist);
    k_prefix<<<313, 256, 0, stream>>>(hist, deg, bsum);
    k_scan2<<<1, 128, 0, stream>>>(bsum, boff, row_start);
    k_scan3<<<79, 256, 0, stream>>>(deg, boff, row_start, inv_deg);
    k_fill2<<<NB, 256, 0, stream>>>(ei, row_start, hist, csr);
    k_agg<<<5000, 256, 0, stream>>>((const uint2*)xb2, row_start, csr, inv_deg,
                                    meanb2);
    dim3 ggrid(313, 4);
    k_gemm<<<ggrid, 256, 0, stream>>>((const uint4*)meanb2, (const uint4*)xb2,
                                      (const uint4*)w1lb4, (const uint4*)w1rb4,
                                      b1, w2l, w2r, s1, t1);
    k_layer2<<<5000, 256, 0, stream>>>(row_start, csr, inv_deg, s1, t1, b2,
                                       fcw, part);
    k_final<<<1, 256, 0, stream>>>(part, fcb, out);
}